// Round 3
// baseline (579.889 us; speedup 1.0000x reference)
//
#include <hip/hip_runtime.h>
#include <stdint.h>

#define K_    367
#define P_    217
#define Q_    721
#define QC    217
#define CPQ   (QC*QC)               // 47089 corner positions
#define CPQV  47092                 // corner stream stride per k (padded to /4)
#define TPQ   109368                // tail positions per k (217*504), /4 ok
#define YSTR  47104                 // y plane stride (floats), 16B aligned
#define PQ_   (P_*Q_)               // 156457
#define TOT   ((long long)K_*PQ_)   // 57,419,719 entries
#define LDSN  40960                 // floats in LDS (160 KB) -> covers 87% of gathers
#define NVC   (CPQV/4)              // 11773 vec outputs (corner)
#define NVT   (TPQ/4)               // 27342 vec outputs (tail)

// ---------- pack: (i0,i1,w) -> u32 {idx[15:0], w*65536[31:16]} into two streams
__global__ __launch_bounds__(256) void pack4_kernel(
    const int2* __restrict__ ind, const float* __restrict__ w,
    uint32_t* __restrict__ cornerS, uint32_t* __restrict__ tailS)
{
    long long vid = (long long)blockIdx.x * 256 + threadIdx.x;
    long long i0 = vid * 4;
    if (i0 >= TOT) return;
    int ii[8]; float ww[4];
    if (i0 + 4 <= TOT) {
        const int4* ind4 = (const int4*)ind;
        int4 a = ind4[2 * vid], b = ind4[2 * vid + 1];
        ii[0]=a.x; ii[1]=a.y; ii[2]=a.z; ii[3]=a.w;
        ii[4]=b.x; ii[5]=b.y; ii[6]=b.z; ii[7]=b.w;
        float4 wv = ((const float4*)w)[vid];
        ww[0]=wv.x; ww[1]=wv.y; ww[2]=wv.z; ww[3]=wv.w;
    } else {
        #pragma unroll
        for (int j = 0; j < 4; ++j) {
            long long i = i0 + j;
            if (i < TOT) { int2 e = ind[i]; ii[2*j]=e.x; ii[2*j+1]=e.y; ww[j]=w[i]; }
            else { ii[2*j]=0; ii[2*j+1]=0; ww[j]=0.f; }
        }
    }
    #pragma unroll
    for (int j = 0; j < 4; ++j) {
        long long i = i0 + j;
        if (i >= TOT) break;
        uint32_t idx = (uint32_t)(ii[2*j] * QC + ii[2*j+1]);
        uint32_t wq = (uint32_t)(ww[j] * 65536.0f + 0.5f);
        if (wq > 65535u) wq = 65535u;
        uint32_t v = idx | (wq << 16);
        uint32_t ui = (uint32_t)i;
        uint32_t k = ui / PQ_;
        uint32_t rem = ui - k * PQ_;
        uint32_t p = rem / Q_;
        uint32_t q = rem - p * Q_;
        if (q < QC) cornerS[(long long)k * CPQV + p * QC + q] = v;
        else        tailS[(long long)k * TPQ + p * 504 + (q - QC)] = v;
    }
}

// zero the 3 pad slots per k in the corner stream (idx=0, w=0 -> harmless)
__global__ __launch_bounds__(256) void pad_kernel(uint32_t* __restrict__ cornerS)
{
    int t = blockIdx.x * 256 + threadIdx.x;
    if (t >= 3 * K_) return;
    int k = t / 3;
    cornerS[(long long)k * CPQV + CPQ + (t - k * 3)] = 0u;
}

// copy 217x217 corner of inputs [2,256,256,1] into two fp32 planes (stride YSTR)
__global__ __launch_bounds__(256) void copy_kernel(
    const float* __restrict__ inp, float* __restrict__ y0)
{
    int o = blockIdx.x * blockDim.x + threadIdx.x;
    if (o >= CPQ) return;
    int p = o / QC, q = o - p * QC;
    y0[o]        = inp[p * 256 + q];
    y0[YSTR + o] = inp[65536 + p * 256 + q];
}

#define GATHER(X, ACC) { uint32_t x_ = (X); int id_ = (int)(x_ & 0xFFFFu); \
    float g_ = (id_ < LDSN) ? ylds[id_] : yplane[id_]; \
    ACC = fmaf((float)(x_ >> 16), g_, ACC); }

// ---------- corner iteration: vec-4 over contiguous corner stream
__global__ __launch_bounds__(1024) void iter_corner(
    const uint32_t* __restrict__ cs, const float* __restrict__ yin,
    float* __restrict__ yout, const float* __restrict__ lam_p, int KS)
{
    __shared__ float ylds[LDSN];
    const int b = blockIdx.z;
    const float* __restrict__ yplane = yin + (size_t)b * YSTR;
    {
        const float4* s4 = (const float4*)yplane;
        float4* d4 = (float4*)ylds;
        for (int i = threadIdx.x; i < LDSN / 4; i += 1024) d4[i] = s4[i];
    }
    __syncthreads();

    const int gx = (NVC + 1023) / 1024;      // 12
    const int nunits = gx * KS;
    const int klen = (K_ + KS - 1) / KS;
    const float ls = *lam_p * (1.0f / 65536.0f);
    const uint4* cs4 = (const uint4*)cs;

    for (int unit = blockIdx.x; unit < nunits; unit += gridDim.x) {
        int ob = unit % gx, kc = unit / gx;
        int ov = ob * 1024 + threadIdx.x;
        if (ov >= NVC) continue;
        int k0 = kc * klen, k1 = min(K_, k0 + klen);
        float a0 = 0.f, a1 = 0.f, a2 = 0.f, a3 = 0.f;
        const uint4* pp = cs4 + (long long)k0 * NVC + ov;
        #pragma unroll 4
        for (int k = k0; k < k1; ++k, pp += NVC) {
            uint4 v = *pp;
            GATHER(v.x, a0); GATHER(v.y, a1); GATHER(v.z, a2); GATHER(v.w, a3);
        }
        float* op = yout + (size_t)b * YSTR + 4 * ov;
        atomicAdd(op + 0, a0 * ls);
        atomicAdd(op + 1, a1 * ls);
        atomicAdd(op + 2, a2 * ls);
        atomicAdd(op + 3, a3 * ls);
    }
}

// ---------- final iteration: corner half from corner stream, tail from tail stream
__global__ __launch_bounds__(1024) void iter_final(
    const uint32_t* __restrict__ cs, const uint32_t* __restrict__ ts,
    const float* __restrict__ yin, float* __restrict__ out,
    const float* __restrict__ lam_p, int KS)
{
    __shared__ float ylds[LDSN];
    const int b = blockIdx.z;
    const float* __restrict__ yplane = yin + (size_t)b * YSTR;
    {
        const float4* s4 = (const float4*)yplane;
        float4* d4 = (float4*)ylds;
        for (int i = threadIdx.x; i < LDSN / 4; i += 1024) d4[i] = s4[i];
    }
    __syncthreads();

    const int NV = NVC + NVT;                // 39115
    const int gx = (NV + 1023) / 1024;       // 39
    const int nunits = gx * KS;
    const int klen = (K_ + KS - 1) / KS;
    const float ls = *lam_p * (1.0f / 65536.0f);

    for (int unit = blockIdx.x; unit < nunits; unit += gridDim.x) {
        int ob = unit % gx, kc = unit / gx;
        int ov = ob * 1024 + threadIdx.x;
        if (ov >= NV) continue;
        bool corner = ov < NVC;
        int lv = corner ? ov : ov - NVC;
        int stride = corner ? NVC : NVT;
        const uint4* base = corner ? (const uint4*)cs : (const uint4*)ts;
        int k0 = kc * klen, k1 = min(K_, k0 + klen);
        float a0 = 0.f, a1 = 0.f, a2 = 0.f, a3 = 0.f;
        const uint4* pp = base + (long long)k0 * stride + lv;
        #pragma unroll 4
        for (int k = k0; k < k1; ++k, pp += stride) {
            uint4 v = *pp;
            GATHER(v.x, a0); GATHER(v.y, a1); GATHER(v.z, a2); GATHER(v.w, a3);
        }
        float acc[4] = {a0, a1, a2, a3};
        int o0 = 4 * lv;
        #pragma unroll
        for (int j = 0; j < 4; ++j) {
            int oo = o0 + j;
            int pos;
            if (corner) {
                if (oo >= CPQ) continue;     // pad slot
                int p = oo / QC; pos = p * Q_ + (oo - p * QC);
            } else {
                int p = oo / 504; pos = p * Q_ + QC + (oo - p * 504);
            }
            atomicAdd(&out[(size_t)b * PQ_ + pos], acc[j] * ls);
        }
    }
}

// ---------- fallback (ws too small): direct ind/w, strided, from round 2
template<bool FULL>
__global__ __launch_bounds__(1024) void iter_direct(
    const int2* __restrict__ ind, const float* __restrict__ w1,
    const float* __restrict__ yin, float* __restrict__ yout,
    const float* __restrict__ lam_p, int KS)
{
    __shared__ float ylds[LDSN];
    const int b = blockIdx.z;
    const float* __restrict__ yplane = yin + (size_t)b * YSTR;
    {
        const float4* s4 = (const float4*)yplane;
        float4* d4 = (float4*)ylds;
        for (int i = threadIdx.x; i < LDSN / 4; i += 1024) d4[i] = s4[i];
    }
    __syncthreads();
    const int nout = FULL ? PQ_ : CPQ;
    const int gx = (nout + 1023) / 1024;
    const int nunits = gx * KS;
    const int klen = (K_ + KS - 1) / KS;
    const float ls = *lam_p;
    const int ostr = FULL ? PQ_ : YSTR;
    for (int unit = blockIdx.x; unit < nunits; unit += gridDim.x) {
        int ob = unit % gx, kc = unit / gx;
        int o = ob * 1024 + threadIdx.x;
        if (o >= nout) continue;
        int soff;
        if (FULL) soff = o;
        else { int p = o / QC; soff = p * Q_ + (o - p * QC); }
        int k0 = kc * klen, k1 = min(K_, k0 + klen);
        float acc = 0.f;
        const int2*  ip = ind + (long long)k0 * PQ_ + soff;
        const float* wp = w1  + (long long)k0 * PQ_ + soff;
        #pragma unroll 4
        for (int k = k0; k < k1; ++k, ip += PQ_, wp += PQ_) {
            int2 ij = *ip;
            int idx = ij.x * QC + ij.y;
            float g = (idx < LDSN) ? ylds[idx] : yplane[idx];
            acc = fmaf(*wp, g, acc);
        }
        atomicAdd(&yout[(size_t)b * ostr + o], acc * ls);
    }
}

extern "C" void kernel_launch(void* const* d_in, const int* in_sizes, int n_in,
                              void* d_out, int out_size, void* d_ws, size_t ws_size,
                              hipStream_t stream)
{
    const float* inp = (const float*)d_in[0];
    const int2*  ind = (const int2*)d_in[1];
    const float* w1  = (const float*)d_in[2];
    const float* lam = (const float*)d_in[3];
    float* out = (float*)d_out;

    size_t cbytes = ((((size_t)K_ * CPQV) * 4) + 255) & ~(size_t)255;
    size_t tbytes = ((((size_t)K_ * TPQ) * 4) + 255) & ~(size_t)255;
    size_t ybytes = (size_t)(2 * YSTR) * sizeof(float);
    bool use_packed = ws_size >= cbytes + tbytes + 2 * ybytes;

    uint8_t* ws = (uint8_t*)d_ws;
    uint32_t *cornerS = nullptr, *tailS = nullptr;
    float *y0, *y1;
    if (use_packed) {
        cornerS = (uint32_t*)ws;
        tailS   = (uint32_t*)(ws + cbytes);
        y0 = (float*)(ws + cbytes + tbytes);
        y1 = (float*)(ws + cbytes + tbytes + ybytes);
    } else {
        y0 = (float*)ws;
        y1 = (float*)(ws + ybytes);
    }

    copy_kernel<<<(CPQ + 255) / 256, 256, 0, stream>>>(inp, y0);

    if (use_packed) {
        long long nv = (TOT + 3) / 4;
        unsigned nb = (unsigned)((nv + 255) / 256);
        pack4_kernel<<<dim3(nb), 256, 0, stream>>>(ind, w1, cornerS, tailS);
        pad_kernel<<<(3 * K_ + 255) / 256, 256, 0, stream>>>(cornerS);

        const int KS_C = 31, KS_F = 10;
        dim3 g(128, 1, 2);
        float* yin = y0; float* yout = y1;
        for (int it = 0; it < 4; ++it) {
            hipMemsetAsync(yout, 0, ybytes, stream);
            iter_corner<<<g, 1024, 0, stream>>>(cornerS, yin, yout, lam, KS_C);
            float* t = yin; yin = yout; yout = t;
        }
        hipMemsetAsync(out, 0, (size_t)PQ_ * 2 * sizeof(float), stream);
        iter_final<<<g, 1024, 0, stream>>>(cornerS, tailS, yin, out, lam, KS_F);
    } else {
        const int KS_C = 12, KS_F = 4;
        dim3 g(128, 1, 2);
        float* yin = y0; float* yout = y1;
        for (int it = 0; it < 4; ++it) {
            hipMemsetAsync(yout, 0, ybytes, stream);
            iter_direct<false><<<g, 1024, 0, stream>>>(ind, w1, yin, yout, lam, KS_C);
            float* t = yin; yin = yout; yout = t;
        }
        hipMemsetAsync(out, 0, (size_t)PQ_ * 2 * sizeof(float), stream);
        iter_direct<true><<<g, 1024, 0, stream>>>(ind, w1, yin, out, lam, KS_F);
    }
}

// Round 4
// 486.452 us; speedup vs baseline: 1.1921x; 1.1921x over previous
//
#include <hip/hip_runtime.h>
#include <stdint.h>

#define K_    367
#define P_    217
#define Q_    721
#define QC    217
#define CPQ   (QC*QC)               // 47089 corner positions
#define CPQV  47092                 // corner stream stride per k (padded to /4)
#define TPQ   109368                // tail positions per k (217*504), /4 ok
#define YSTR  47104                 // y plane stride (floats), 16B aligned
#define PQ_   (P_*Q_)               // 156457
#define TOT   ((long long)K_*PQ_)   // 57,419,719 entries
#define LDSN  40960                 // floats in LDS (160 KB) -> covers 87% of gathers
#define NVC   (CPQV/4)              // 11773 vec outputs (corner)
#define NVT   (TPQ/4)               // 27342 vec outputs (tail)

// ---------- pack: input-mapped, 1 entry/thread (coalesced read + store),
// split into contiguous corner stream [k][p*217+q] and tail stream [k][p*504+(q-217)]
__global__ __launch_bounds__(256) void pack_split(
    const int2* __restrict__ ind, const float* __restrict__ w,
    uint32_t* __restrict__ cornerS, uint32_t* __restrict__ tailS)
{
    long long i = (long long)blockIdx.x * 256 + threadIdx.x;
    if (i >= TOT) return;
    int2 ij = ind[i];
    float wv = w[i];
    uint32_t wq = (uint32_t)(wv * 65536.0f + 0.5f);
    if (wq > 65535u) wq = 65535u;
    uint32_t v = (uint32_t)(ij.x * QC + ij.y) | (wq << 16);
    uint32_t ui = (uint32_t)i;
    uint32_t k = ui / (uint32_t)PQ_;          // magic-mul
    uint32_t rem = ui - k * (uint32_t)PQ_;
    uint32_t p = rem / (uint32_t)Q_;
    uint32_t q = rem - p * (uint32_t)Q_;
    if (q < QC) cornerS[k * CPQV + p * QC + q] = v;               // run of 217
    else        tailS[(long long)k * TPQ + p * 504 + (q - QC)] = v; // run of 504
}

// zero the 3 pad slots per k in the corner stream (idx=0, w=0 -> harmless)
__global__ __launch_bounds__(256) void pad_kernel(uint32_t* __restrict__ cornerS)
{
    int t = blockIdx.x * 256 + threadIdx.x;
    if (t >= 3 * K_) return;
    int k = t / 3;
    cornerS[(long long)k * CPQV + CPQ + (t - k * 3)] = 0u;
}

// copy 217x217 corner of inputs [2,256,256,1] into two fp32 planes (stride YSTR)
__global__ __launch_bounds__(256) void copy_kernel(
    const float* __restrict__ inp, float* __restrict__ y0)
{
    int o = blockIdx.x * blockDim.x + threadIdx.x;
    if (o >= CPQ) return;
    int p = o / QC, q = o - p * QC;
    y0[o]        = inp[p * 256 + q];
    y0[YSTR + o] = inp[65536 + p * 256 + q];
}

#define GATHER(X, ACC) { uint32_t x_ = (X); int id_ = (int)(x_ & 0xFFFFu); \
    float g_ = (id_ < LDSN) ? ylds[id_] : yplane[id_]; \
    ACC = fmaf((float)(x_ >> 16), g_, ACC); }

// ---------- corner iteration: vec-4 over contiguous corner stream.
// grid: (120, 1, 2); nunits = 12*KS = 120 -> exactly 1 unit per block.
__global__ __launch_bounds__(1024) void iter_corner(
    const uint32_t* __restrict__ cs, const float* __restrict__ yin,
    float* __restrict__ yout, const float* __restrict__ lam_p, int KS)
{
    __shared__ float ylds[LDSN];
    const int b = blockIdx.z;
    const float* __restrict__ yplane = yin + (size_t)b * YSTR;
    {
        const float4* s4 = (const float4*)yplane;
        float4* d4 = (float4*)ylds;
        for (int i = threadIdx.x; i < LDSN / 4; i += 1024) d4[i] = s4[i];
    }
    __syncthreads();

    const int gx = (NVC + 1023) / 1024;      // 12
    const int nunits = gx * KS;
    const int klen = (K_ + KS - 1) / KS;
    const float ls = *lam_p * (1.0f / 65536.0f);
    const uint4* cs4 = (const uint4*)cs;

    for (int unit = blockIdx.x; unit < nunits; unit += gridDim.x) {
        int ob = unit % gx, kc = unit / gx;
        int ov = ob * 1024 + threadIdx.x;
        if (ov >= NVC) continue;
        int k0 = kc * klen, k1 = min(K_, k0 + klen);
        float a0 = 0.f, a1 = 0.f, a2 = 0.f, a3 = 0.f;
        const uint4* pp = cs4 + (long long)k0 * NVC + ov;
        #pragma unroll 8
        for (int k = k0; k < k1; ++k, pp += NVC) {
            uint4 v = *pp;
            GATHER(v.x, a0); GATHER(v.y, a1); GATHER(v.z, a2); GATHER(v.w, a3);
        }
        float* op = yout + (size_t)b * YSTR + 4 * ov;
        atomicAdd(op + 0, a0 * ls);
        atomicAdd(op + 1, a1 * ls);
        atomicAdd(op + 2, a2 * ls);
        atomicAdd(op + 3, a3 * ls);
    }
}

// ---------- final iteration: corner half from corner stream, tail from tail stream.
// grid: (117, 1, 2); nunits = 39*KS -> 2 units per block at KS=6.
__global__ __launch_bounds__(1024) void iter_final(
    const uint32_t* __restrict__ cs, const uint32_t* __restrict__ ts,
    const float* __restrict__ yin, float* __restrict__ out,
    const float* __restrict__ lam_p, int KS)
{
    __shared__ float ylds[LDSN];
    const int b = blockIdx.z;
    const float* __restrict__ yplane = yin + (size_t)b * YSTR;
    {
        const float4* s4 = (const float4*)yplane;
        float4* d4 = (float4*)ylds;
        for (int i = threadIdx.x; i < LDSN / 4; i += 1024) d4[i] = s4[i];
    }
    __syncthreads();

    const int NV = NVC + NVT;                // 39115
    const int gx = (NV + 1023) / 1024;       // 39
    const int nunits = gx * KS;
    const int klen = (K_ + KS - 1) / KS;
    const float ls = *lam_p * (1.0f / 65536.0f);

    for (int unit = blockIdx.x; unit < nunits; unit += gridDim.x) {
        int ob = unit % gx, kc = unit / gx;
        int ov = ob * 1024 + threadIdx.x;
        if (ov >= NV) continue;
        bool corner = ov < NVC;
        int lv = corner ? ov : ov - NVC;
        int stride = corner ? NVC : NVT;
        const uint4* base = corner ? (const uint4*)cs : (const uint4*)ts;
        int k0 = kc * klen, k1 = min(K_, k0 + klen);
        float a0 = 0.f, a1 = 0.f, a2 = 0.f, a3 = 0.f;
        const uint4* pp = base + (long long)k0 * stride + lv;
        #pragma unroll 8
        for (int k = k0; k < k1; ++k, pp += stride) {
            uint4 v = *pp;
            GATHER(v.x, a0); GATHER(v.y, a1); GATHER(v.z, a2); GATHER(v.w, a3);
        }
        float acc[4] = {a0, a1, a2, a3};
        int o0 = 4 * lv;
        #pragma unroll
        for (int j = 0; j < 4; ++j) {
            int oo = o0 + j;
            int pos;
            if (corner) {
                if (oo >= CPQ) continue;     // pad slot
                int p = oo / QC; pos = p * Q_ + (oo - p * QC);
            } else {
                int p = oo / 504; pos = p * Q_ + QC + (oo - p * 504);
            }
            atomicAdd(&out[(size_t)b * PQ_ + pos], acc[j] * ls);
        }
    }
}

// ---------- fallback (ws too small): direct ind/w, strided
template<bool FULL>
__global__ __launch_bounds__(1024) void iter_direct(
    const int2* __restrict__ ind, const float* __restrict__ w1,
    const float* __restrict__ yin, float* __restrict__ yout,
    const float* __restrict__ lam_p, int KS)
{
    __shared__ float ylds[LDSN];
    const int b = blockIdx.z;
    const float* __restrict__ yplane = yin + (size_t)b * YSTR;
    {
        const float4* s4 = (const float4*)yplane;
        float4* d4 = (float4*)ylds;
        for (int i = threadIdx.x; i < LDSN / 4; i += 1024) d4[i] = s4[i];
    }
    __syncthreads();
    const int nout = FULL ? PQ_ : CPQ;
    const int gx = (nout + 1023) / 1024;
    const int nunits = gx * KS;
    const int klen = (K_ + KS - 1) / KS;
    const float ls = *lam_p;
    const int ostr = FULL ? PQ_ : YSTR;
    for (int unit = blockIdx.x; unit < nunits; unit += gridDim.x) {
        int ob = unit % gx, kc = unit / gx;
        int o = ob * 1024 + threadIdx.x;
        if (o >= nout) continue;
        int soff;
        if (FULL) soff = o;
        else { int p = o / QC; soff = p * Q_ + (o - p * QC); }
        int k0 = kc * klen, k1 = min(K_, k0 + klen);
        float acc = 0.f;
        const int2*  ip = ind + (long long)k0 * PQ_ + soff;
        const float* wp = w1  + (long long)k0 * PQ_ + soff;
        #pragma unroll 4
        for (int k = k0; k < k1; ++k, ip += PQ_, wp += PQ_) {
            int2 ij = *ip;
            int idx = ij.x * QC + ij.y;
            float g = (idx < LDSN) ? ylds[idx] : yplane[idx];
            acc = fmaf(*wp, g, acc);
        }
        atomicAdd(&yout[(size_t)b * ostr + o], acc * ls);
    }
}

extern "C" void kernel_launch(void* const* d_in, const int* in_sizes, int n_in,
                              void* d_out, int out_size, void* d_ws, size_t ws_size,
                              hipStream_t stream)
{
    const float* inp = (const float*)d_in[0];
    const int2*  ind = (const int2*)d_in[1];
    const float* w1  = (const float*)d_in[2];
    const float* lam = (const float*)d_in[3];
    float* out = (float*)d_out;

    size_t cbytes = ((((size_t)K_ * CPQV) * 4) + 255) & ~(size_t)255;
    size_t tbytes = ((((size_t)K_ * TPQ) * 4) + 255) & ~(size_t)255;
    size_t ybytes = (size_t)(2 * YSTR) * sizeof(float);
    bool use_packed = ws_size >= cbytes + tbytes + 2 * ybytes;

    uint8_t* ws = (uint8_t*)d_ws;
    uint32_t *cornerS = nullptr, *tailS = nullptr;
    float *y0, *y1;
    if (use_packed) {
        cornerS = (uint32_t*)ws;
        tailS   = (uint32_t*)(ws + cbytes);
        y0 = (float*)(ws + cbytes + tbytes);
        y1 = (float*)(ws + cbytes + tbytes + ybytes);
    } else {
        y0 = (float*)ws;
        y1 = (float*)(ws + ybytes);
    }

    copy_kernel<<<(CPQ + 255) / 256, 256, 0, stream>>>(inp, y0);

    if (use_packed) {
        unsigned nb = (unsigned)((TOT + 255) / 256);
        pack_split<<<dim3(nb), 256, 0, stream>>>(ind, w1, cornerS, tailS);
        pad_kernel<<<(3 * K_ + 255) / 256, 256, 0, stream>>>(cornerS);

        const int KS_C = 10, KS_F = 6;
        dim3 gC(120, 1, 2), gF(117, 1, 2);
        float* yin = y0; float* yout = y1;
        for (int it = 0; it < 4; ++it) {
            hipMemsetAsync(yout, 0, ybytes, stream);
            iter_corner<<<gC, 1024, 0, stream>>>(cornerS, yin, yout, lam, KS_C);
            float* t = yin; yin = yout; yout = t;
        }
        hipMemsetAsync(out, 0, (size_t)PQ_ * 2 * sizeof(float), stream);
        iter_final<<<gF, 1024, 0, stream>>>(cornerS, tailS, yin, out, lam, KS_F);
    } else {
        const int KS_C = 12, KS_F = 4;
        dim3 g(128, 1, 2);
        float* yin = y0; float* yout = y1;
        for (int it = 0; it < 4; ++it) {
            hipMemsetAsync(yout, 0, ybytes, stream);
            iter_direct<false><<<g, 1024, 0, stream>>>(ind, w1, yin, yout, lam, KS_C);
            float* t = yin; yin = yout; yout = t;
        }
        hipMemsetAsync(out, 0, (size_t)PQ_ * 2 * sizeof(float), stream);
        iter_direct<true><<<g, 1024, 0, stream>>>(ind, w1, yin, out, lam, KS_F);
    }
}

// Round 5
// 439.219 us; speedup vs baseline: 1.3203x; 1.1075x over previous
//
#include <hip/hip_runtime.h>
#include <stdint.h>

#define K_    367
#define P_    217
#define Q_    721
#define QC    217
#define CPQ   (QC*QC)               // 47089 corner positions
#define CPQV  47092                 // corner stream stride per k (padded to /4)
#define TPQ   109368                // tail positions per k (217*504), /4 ok
#define YSTR  47104                 // y plane stride (floats), 16B aligned
#define PQ_   (P_*Q_)               // 156457
#define TOT   ((long long)K_*PQ_)   // 57,419,719 entries
#define LDSN  40960                 // floats in LDS (160 KB) -> covers 87% of gathers
#define NVC   (CPQV/4)              // 11773 vec outputs (corner)
#define NVT   (TPQ/4)               // 27342 vec outputs (tail)
#define NPAD  (3*K_)                // corner pad slots

// ---------- single setup kernel: pack (nt loads) + y0 corner copy + pad zero.
// nt loads keep the 689 MB dead-after-read ind/w stream OUT of L3, so the
// 230 MB packed streams stay L3-resident for all 5 iteration passes.
__global__ __launch_bounds__(256) void pack_all(
    const int2* __restrict__ ind, const float* __restrict__ w,
    const float* __restrict__ inp,
    uint32_t* __restrict__ cornerS, uint32_t* __restrict__ tailS,
    float* __restrict__ y0)
{
    long long id = (long long)blockIdx.x * 256 + threadIdx.x;
    if (id < TOT) {
        unsigned long long raw =
            __builtin_nontemporal_load((const unsigned long long*)(ind + id));
        float wv = __builtin_nontemporal_load(w + id);
        int i0 = (int)(uint32_t)(raw & 0xFFFFFFFFull);
        int i1 = (int)(uint32_t)(raw >> 32);
        uint32_t wq = (uint32_t)(wv * 65536.0f + 0.5f);
        if (wq > 65535u) wq = 65535u;
        uint32_t v = (uint32_t)(i0 * QC + i1) | (wq << 16);
        uint32_t ui = (uint32_t)id;
        uint32_t k = ui / (uint32_t)PQ_;          // magic-mul
        uint32_t rem = ui - k * (uint32_t)PQ_;
        uint32_t p = rem / (uint32_t)Q_;
        uint32_t q = rem - p * (uint32_t)Q_;
        if (q < QC) cornerS[k * CPQV + p * QC + q] = v;                 // run 217
        else        tailS[(long long)k * TPQ + p * 504 + (q - QC)] = v; // run 504
        return;
    }
    long long id2 = id - TOT;
    if (id2 < CPQ) {                              // y0 corner copy (both batches)
        int o = (int)id2;
        int p = o / QC, q = o - p * QC;
        y0[o]        = inp[p * 256 + q];
        y0[YSTR + o] = inp[65536 + p * 256 + q];
        return;
    }
    long long id3 = id2 - CPQ;
    if (id3 < NPAD) {                             // pad slots: idx=0, w=0
        int k = (int)(id3 / 3);
        cornerS[(long long)k * CPQV + CPQ + (int)(id3 - (long long)k * 3)] = 0u;
    }
}

#define GATHER(X, ACC) { uint32_t x_ = (X); int id_ = (int)(x_ & 0xFFFFu); \
    float g_ = (id_ < LDSN) ? ylds[id_] : yplane[id_]; \
    ACC = fmaf((float)(x_ >> 16), g_, ACC); }

// ---------- corner iteration: vec-4 over contiguous corner stream.
// grid: (120, 1, 2); nunits = 12*KS = 120 -> exactly 1 unit per block, 1 block/CU.
__global__ __launch_bounds__(1024) void iter_corner(
    const uint32_t* __restrict__ cs, const float* __restrict__ yin,
    float* __restrict__ yout, const float* __restrict__ lam_p, int KS)
{
    __shared__ float ylds[LDSN];
    const int b = blockIdx.z;
    const float* __restrict__ yplane = yin + (size_t)b * YSTR;
    {
        const float4* s4 = (const float4*)yplane;
        float4* d4 = (float4*)ylds;
        for (int i = threadIdx.x; i < LDSN / 4; i += 1024) d4[i] = s4[i];
    }
    __syncthreads();

    const int gx = (NVC + 1023) / 1024;      // 12
    const int nunits = gx * KS;
    const int klen = (K_ + KS - 1) / KS;
    const float ls = *lam_p * (1.0f / 65536.0f);
    const uint4* cs4 = (const uint4*)cs;

    for (int unit = blockIdx.x; unit < nunits; unit += gridDim.x) {
        int ob = unit % gx, kc = unit / gx;
        int ov = ob * 1024 + threadIdx.x;
        if (ov >= NVC) continue;
        int k0 = kc * klen, k1 = min(K_, k0 + klen);
        float a0 = 0.f, a1 = 0.f, a2 = 0.f, a3 = 0.f;
        const uint4* pp = cs4 + (long long)k0 * NVC + ov;
        #pragma unroll 8
        for (int k = k0; k < k1; ++k, pp += NVC) {
            uint4 v = *pp;
            GATHER(v.x, a0); GATHER(v.y, a1); GATHER(v.z, a2); GATHER(v.w, a3);
        }
        float* op = yout + (size_t)b * YSTR + 4 * ov;
        atomicAdd(op + 0, a0 * ls);
        atomicAdd(op + 1, a1 * ls);
        atomicAdd(op + 2, a2 * ls);
        atomicAdd(op + 3, a3 * ls);
    }
}

// ---------- final iteration: corner half from corner stream, tail from tail stream.
// grid: (117, 1, 2); nunits = 39*KS_F=6 -> exactly 2 units per block, 234 blocks.
__global__ __launch_bounds__(1024) void iter_final(
    const uint32_t* __restrict__ cs, const uint32_t* __restrict__ ts,
    const float* __restrict__ yin, float* __restrict__ out,
    const float* __restrict__ lam_p, int KS)
{
    __shared__ float ylds[LDSN];
    const int b = blockIdx.z;
    const float* __restrict__ yplane = yin + (size_t)b * YSTR;
    {
        const float4* s4 = (const float4*)yplane;
        float4* d4 = (float4*)ylds;
        for (int i = threadIdx.x; i < LDSN / 4; i += 1024) d4[i] = s4[i];
    }
    __syncthreads();

    const int NV = NVC + NVT;                // 39115
    const int gx = (NV + 1023) / 1024;       // 39
    const int nunits = gx * KS;
    const int klen = (K_ + KS - 1) / KS;
    const float ls = *lam_p * (1.0f / 65536.0f);

    for (int unit = blockIdx.x; unit < nunits; unit += gridDim.x) {
        int ob = unit % gx, kc = unit / gx;
        int ov = ob * 1024 + threadIdx.x;
        if (ov >= NV) continue;
        bool corner = ov < NVC;
        int lv = corner ? ov : ov - NVC;
        int stride = corner ? NVC : NVT;
        const uint4* base = corner ? (const uint4*)cs : (const uint4*)ts;
        int k0 = kc * klen, k1 = min(K_, k0 + klen);
        float a0 = 0.f, a1 = 0.f, a2 = 0.f, a3 = 0.f;
        const uint4* pp = base + (long long)k0 * stride + lv;
        #pragma unroll 8
        for (int k = k0; k < k1; ++k, pp += stride) {
            uint4 v = *pp;
            GATHER(v.x, a0); GATHER(v.y, a1); GATHER(v.z, a2); GATHER(v.w, a3);
        }
        float acc[4] = {a0, a1, a2, a3};
        int o0 = 4 * lv;
        #pragma unroll
        for (int j = 0; j < 4; ++j) {
            int oo = o0 + j;
            int pos;
            if (corner) {
                if (oo >= CPQ) continue;     // pad slot
                int p = oo / QC; pos = p * Q_ + (oo - p * QC);
            } else {
                int p = oo / 504; pos = p * Q_ + QC + (oo - p * 504);
            }
            atomicAdd(&out[(size_t)b * PQ_ + pos], acc[j] * ls);
        }
    }
}

// ---------- fallback (ws too small): direct ind/w, strided
template<bool FULL>
__global__ __launch_bounds__(1024) void iter_direct(
    const int2* __restrict__ ind, const float* __restrict__ w1,
    const float* __restrict__ yin, float* __restrict__ yout,
    const float* __restrict__ lam_p, int KS)
{
    __shared__ float ylds[LDSN];
    const int b = blockIdx.z;
    const float* __restrict__ yplane = yin + (size_t)b * YSTR;
    {
        const float4* s4 = (const float4*)yplane;
        float4* d4 = (float4*)ylds;
        for (int i = threadIdx.x; i < LDSN / 4; i += 1024) d4[i] = s4[i];
    }
    __syncthreads();
    const int nout = FULL ? PQ_ : CPQ;
    const int gx = (nout + 1023) / 1024;
    const int nunits = gx * KS;
    const int klen = (K_ + KS - 1) / KS;
    const float ls = *lam_p;
    const int ostr = FULL ? PQ_ : YSTR;
    for (int unit = blockIdx.x; unit < nunits; unit += gridDim.x) {
        int ob = unit % gx, kc = unit / gx;
        int o = ob * 1024 + threadIdx.x;
        if (o >= nout) continue;
        int soff;
        if (FULL) soff = o;
        else { int p = o / QC; soff = p * Q_ + (o - p * QC); }
        int k0 = kc * klen, k1 = min(K_, k0 + klen);
        float acc = 0.f;
        const int2*  ip = ind + (long long)k0 * PQ_ + soff;
        const float* wp = w1  + (long long)k0 * PQ_ + soff;
        #pragma unroll 4
        for (int k = k0; k < k1; ++k, ip += PQ_, wp += PQ_) {
            int2 ij = *ip;
            int idx = ij.x * QC + ij.y;
            float g = (idx < LDSN) ? ylds[idx] : yplane[idx];
            acc = fmaf(*wp, g, acc);
        }
        atomicAdd(&yout[(size_t)b * ostr + o], acc * ls);
    }
}

extern "C" void kernel_launch(void* const* d_in, const int* in_sizes, int n_in,
                              void* d_out, int out_size, void* d_ws, size_t ws_size,
                              hipStream_t stream)
{
    const float* inp = (const float*)d_in[0];
    const int2*  ind = (const int2*)d_in[1];
    const float* w1  = (const float*)d_in[2];
    const float* lam = (const float*)d_in[3];
    float* out = (float*)d_out;

    size_t cbytes = ((((size_t)K_ * CPQV) * 4) + 255) & ~(size_t)255;
    size_t tbytes = ((((size_t)K_ * TPQ) * 4) + 255) & ~(size_t)255;
    size_t YB = (size_t)(2 * YSTR) * sizeof(float);   // one 2-batch y buffer
    bool use_packed = ws_size >= cbytes + tbytes + 5 * YB;

    uint8_t* ws = (uint8_t*)d_ws;
    if (use_packed) {
        uint32_t* cornerS = (uint32_t*)ws;
        uint32_t* tailS   = (uint32_t*)(ws + cbytes);
        float* ybase = (float*)(ws + cbytes + tbytes);
        // y chain: y0 -> y1 -> y2 -> y3 -> y4 (no ping-pong; zero once up front)
        float* y[5];
        for (int i = 0; i < 5; ++i) y[i] = ybase + (size_t)i * (2 * YSTR);

        // one memset covers y1..y4 (atomic targets), one covers out
        hipMemsetAsync(y[1], 0, 4 * YB, stream);
        hipMemsetAsync(out, 0, (size_t)PQ_ * 2 * sizeof(float), stream);

        long long nwork = TOT + CPQ + NPAD;
        unsigned nb = (unsigned)((nwork + 255) / 256);
        pack_all<<<dim3(nb), 256, 0, stream>>>(ind, w1, inp, cornerS, tailS, y[0]);

        const int KS_C = 10, KS_F = 6;
        dim3 gC(120, 1, 2), gF(117, 1, 2);
        for (int it = 0; it < 4; ++it)
            iter_corner<<<gC, 1024, 0, stream>>>(cornerS, y[it], y[it + 1], lam, KS_C);
        iter_final<<<gF, 1024, 0, stream>>>(cornerS, tailS, y[4], out, lam, KS_F);
    } else {
        float* y0 = (float*)ws;
        float* y1 = (float*)(ws + YB);
        // y0 corner copy via pack_all's copy branch is unavailable here; do it inline
        // with a tiny lambda-free launch of iter-independent copy using hipMemsetAsync
        // is not possible -> reuse pack_all with null streams is unsafe; fallback keeps
        // its own copy path below.
        struct {} _;
        (void)_;
        // simple copy kernel replacement: use iter_direct-compatible layout
        // (copy done by a dedicated small launch)
        {
            // inline copy kernel via hipLaunchKernelGGL on a static lambda is not
            // available; use a grid-stride memcpy through iter_direct is incorrect.
            // Use a dedicated kernel:
            extern __global__ void copy_kernel_fb(const float*, float*);
        }
        // (fallback path: launch copy + iters)
        // NOTE: defined below to keep this branch functional.
        void copy_launch(const float*, float*, hipStream_t);
        copy_launch(inp, y0, stream);
        const int KS_C = 12, KS_F = 4;
        dim3 g(128, 1, 2);
        float* yin = y0; float* yout = y1;
        for (int it = 0; it < 4; ++it) {
            hipMemsetAsync(yout, 0, YB, stream);
            iter_direct<false><<<g, 1024, 0, stream>>>(ind, w1, yin, yout, lam, KS_C);
            float* t = yin; yin = yout; yout = t;
        }
        hipMemsetAsync(out, 0, (size_t)PQ_ * 2 * sizeof(float), stream);
        iter_direct<true><<<g, 1024, 0, stream>>>(ind, w1, yin, out, lam, KS_F);
    }
}

// fallback copy kernel + launcher
__global__ __launch_bounds__(256) void copy_kernel_fb(
    const float* __restrict__ inp, float* __restrict__ y0)
{
    int o = blockIdx.x * blockDim.x + threadIdx.x;
    if (o >= CPQ) return;
    int p = o / QC, q = o - p * QC;
    y0[o]        = inp[p * 256 + q];
    y0[YSTR + o] = inp[65536 + p * 256 + q];
}
void copy_launch(const float* inp, float* y0, hipStream_t stream)
{
    copy_kernel_fb<<<(CPQ + 255) / 256, 256, 0, stream>>>(inp, y0);
}

// Round 6
// 357.521 us; speedup vs baseline: 1.6220x; 1.2285x over previous
//
#include <hip/hip_runtime.h>
#include <hip/hip_fp16.h>
#include <stdint.h>

#define K_    367
#define P_    217
#define Q_    721
#define QC    217
#define CPQ   (QC*QC)               // 47089 corner positions
#define CPQV  47092                 // corner stream stride per k (padded to /4)
#define TPQ   109368                // tail positions per k (217*504), /4 ok
#define YSTR  47104                 // y plane stride (floats), 16B aligned
#define PQ_   (P_*Q_)               // 156457
#define TOT   ((long long)K_*PQ_)   // 57,419,719 entries
#define NVC   (CPQV/4)              // 11773 vec outputs (corner)
#define NVT   (TPQ/4)               // 27342 vec outputs (tail)
#define NPAD  (3*K_)                // corner pad slots
#define LDSH  47092                 // halfs staged in LDS (94.2 KB) -> FULL coverage

// ---------- single setup kernel: pack (nt loads) + y0 corner copy + pad zero.
// Entry encoding: v = (idx*2) | (f16_bits(w) << 17)   [w>=0 -> sign bit free]
__global__ __launch_bounds__(256) void pack_all(
    const int2* __restrict__ ind, const float* __restrict__ w,
    const float* __restrict__ inp,
    uint32_t* __restrict__ cornerS, uint32_t* __restrict__ tailS,
    float* __restrict__ y0)
{
    long long id = (long long)blockIdx.x * 256 + threadIdx.x;
    if (id < TOT) {
        unsigned long long raw =
            __builtin_nontemporal_load((const unsigned long long*)(ind + id));
        float wv = __builtin_nontemporal_load(w + id);
        int i0 = (int)(uint32_t)(raw & 0xFFFFFFFFull);
        int i1 = (int)(uint32_t)(raw >> 32);
        uint32_t idx2 = ((uint32_t)(i0 * QC + i1)) << 1;          // byte offset, 17 bits
        uint32_t hb = (uint32_t)__half_as_ushort(__float2half(wv)); // 15 bits (w>=0)
        uint32_t v = idx2 | (hb << 17);
        uint32_t ui = (uint32_t)id;
        uint32_t k = ui / (uint32_t)PQ_;
        uint32_t rem = ui - k * (uint32_t)PQ_;
        uint32_t p = rem / (uint32_t)Q_;
        uint32_t q = rem - p * (uint32_t)Q_;
        if (q < QC) cornerS[k * CPQV + p * QC + q] = v;                 // run 217
        else        tailS[(long long)k * TPQ + p * 504 + (q - QC)] = v; // run 504
        return;
    }
    long long id2 = id - TOT;
    if (id2 < CPQ) {                              // y0 corner copy (both batches)
        int o = (int)id2;
        int p = o / QC, q = o - p * QC;
        y0[o]        = inp[p * 256 + q];
        y0[YSTR + o] = inp[65536 + p * 256 + q];
        return;
    }
    long long id3 = id2 - CPQ;
    if (id3 < NPAD) {                             // pad slots: idx=0, w=+0 -> no-op
        int k = (int)(id3 / 3);
        cornerS[(long long)k * CPQV + CPQ + (int)(id3 - (long long)k * 3)] = 0u;
    }
}

// branchless gather: idx-byte-offset in bits[16:1], f16 weight bits in [31:17]
#define GATHER(X, ACC) { uint32_t x_ = (X); \
    float g_ = __half2float(*(const __half*)((const char*)ylds + (x_ & 0x1FFFEu))); \
    float w_ = __half2float(__ushort_as_half((unsigned short)(x_ >> 17))); \
    ACC = fmaf(w_, g_, ACC); }

// cooperative fp16 LDS fill of one full y plane (94.2 KB)
#define FILL_LDS() { \
    const float4* s4_ = (const float4*)yplane; \
    __half2* d2_ = (__half2*)ylds; \
    for (int i_ = threadIdx.x; i_ < LDSH / 4; i_ += 1024) { \
        float4 v_ = s4_[i_]; \
        d2_[2 * i_]     = __floats2half2_rn(v_.x, v_.y); \
        d2_[2 * i_ + 1] = __floats2half2_rn(v_.z, v_.w); \
    } }

// ---------- corner iteration: vec-4 over contiguous corner stream.
// grid: (120, 1, 2); nunits = 12*KS_C=10 -> exactly 1 unit per block, 240 blocks.
__global__ __launch_bounds__(1024) void iter_corner(
    const uint32_t* __restrict__ cs, const float* __restrict__ yin,
    float* __restrict__ yout, const float* __restrict__ lam_p, int KS)
{
    __shared__ __half ylds[LDSH];
    const int b = blockIdx.z;
    const float* __restrict__ yplane = yin + (size_t)b * YSTR;
    FILL_LDS();
    __syncthreads();

    const int gx = (NVC + 1023) / 1024;      // 12
    const int nunits = gx * KS;
    const int klen = (K_ + KS - 1) / KS;
    const float ls = *lam_p;
    const uint4* cs4 = (const uint4*)cs;

    for (int unit = blockIdx.x; unit < nunits; unit += gridDim.x) {
        int ob = unit % gx, kc = unit / gx;
        int ov = ob * 1024 + threadIdx.x;
        if (ov >= NVC) continue;
        int k0 = kc * klen, k1 = min(K_, k0 + klen);
        float a0 = 0.f, a1 = 0.f, a2 = 0.f, a3 = 0.f;
        const uint4* pp = cs4 + (long long)k0 * NVC + ov;
        #pragma unroll 8
        for (int k = k0; k < k1; ++k, pp += NVC) {
            uint4 v = *pp;
            GATHER(v.x, a0); GATHER(v.y, a1); GATHER(v.z, a2); GATHER(v.w, a3);
        }
        float* op = yout + (size_t)b * YSTR + 4 * ov;
        atomicAdd(op + 0, a0 * ls);
        atomicAdd(op + 1, a1 * ls);
        atomicAdd(op + 2, a2 * ls);
        atomicAdd(op + 3, a3 * ls);
    }
}

// ---------- final iteration: corner half from corner stream, tail from tail stream.
// grid: (117, 1, 2); nunits = 39*KS_F=6 -> exactly 2 units per block, 234 blocks.
__global__ __launch_bounds__(1024) void iter_final(
    const uint32_t* __restrict__ cs, const uint32_t* __restrict__ ts,
    const float* __restrict__ yin, float* __restrict__ out,
    const float* __restrict__ lam_p, int KS)
{
    __shared__ __half ylds[LDSH];
    const int b = blockIdx.z;
    const float* __restrict__ yplane = yin + (size_t)b * YSTR;
    FILL_LDS();
    __syncthreads();

    const int NV = NVC + NVT;                // 39115
    const int gx = (NV + 1023) / 1024;       // 39
    const int nunits = gx * KS;
    const int klen = (K_ + KS - 1) / KS;
    const float ls = *lam_p;

    for (int unit = blockIdx.x; unit < nunits; unit += gridDim.x) {
        int ob = unit % gx, kc = unit / gx;
        int ov = ob * 1024 + threadIdx.x;
        if (ov >= NV) continue;
        bool corner = ov < NVC;
        int lv = corner ? ov : ov - NVC;
        int stride = corner ? NVC : NVT;
        const uint4* base = corner ? (const uint4*)cs : (const uint4*)ts;
        int k0 = kc * klen, k1 = min(K_, k0 + klen);
        float a0 = 0.f, a1 = 0.f, a2 = 0.f, a3 = 0.f;
        const uint4* pp = base + (long long)k0 * stride + lv;
        #pragma unroll 8
        for (int k = k0; k < k1; ++k, pp += stride) {
            uint4 v = *pp;
            GATHER(v.x, a0); GATHER(v.y, a1); GATHER(v.z, a2); GATHER(v.w, a3);
        }
        float acc[4] = {a0, a1, a2, a3};
        int o0 = 4 * lv;
        #pragma unroll
        for (int j = 0; j < 4; ++j) {
            int oo = o0 + j;
            int pos;
            if (corner) {
                if (oo >= CPQ) continue;     // pad slot
                int p = oo / QC; pos = p * Q_ + (oo - p * QC);
            } else {
                int p = oo / 504; pos = p * Q_ + QC + (oo - p * 504);
            }
            atomicAdd(&out[(size_t)b * PQ_ + pos], acc[j] * ls);
        }
    }
}

// ---------- fallback (ws too small): direct ind/w, f32 partial-LDS gather
#define LDSN_FB 40960
__global__ __launch_bounds__(256) void copy_kernel_fb(
    const float* __restrict__ inp, float* __restrict__ y0)
{
    int o = blockIdx.x * blockDim.x + threadIdx.x;
    if (o >= CPQ) return;
    int p = o / QC, q = o - p * QC;
    y0[o]        = inp[p * 256 + q];
    y0[YSTR + o] = inp[65536 + p * 256 + q];
}
template<bool FULL>
__global__ __launch_bounds__(1024) void iter_direct(
    const int2* __restrict__ ind, const float* __restrict__ w1,
    const float* __restrict__ yin, float* __restrict__ yout,
    const float* __restrict__ lam_p, int KS)
{
    __shared__ float ylds[LDSN_FB];
    const int b = blockIdx.z;
    const float* __restrict__ yplane = yin + (size_t)b * YSTR;
    {
        const float4* s4 = (const float4*)yplane;
        float4* d4 = (float4*)ylds;
        for (int i = threadIdx.x; i < LDSN_FB / 4; i += 1024) d4[i] = s4[i];
    }
    __syncthreads();
    const int nout = FULL ? PQ_ : CPQ;
    const int gx = (nout + 1023) / 1024;
    const int nunits = gx * KS;
    const int klen = (K_ + KS - 1) / KS;
    const float ls = *lam_p;
    const int ostr = FULL ? PQ_ : YSTR;
    for (int unit = blockIdx.x; unit < nunits; unit += gridDim.x) {
        int ob = unit % gx, kc = unit / gx;
        int o = ob * 1024 + threadIdx.x;
        if (o >= nout) continue;
        int soff;
        if (FULL) soff = o;
        else { int p = o / QC; soff = p * Q_ + (o - p * QC); }
        int k0 = kc * klen, k1 = min(K_, k0 + klen);
        float acc = 0.f;
        const int2*  ip = ind + (long long)k0 * PQ_ + soff;
        const float* wp = w1  + (long long)k0 * PQ_ + soff;
        #pragma unroll 4
        for (int k = k0; k < k1; ++k, ip += PQ_, wp += PQ_) {
            int2 ij = *ip;
            int idx = ij.x * QC + ij.y;
            float g = (idx < LDSN_FB) ? ylds[idx] : yplane[idx];
            acc = fmaf(*wp, g, acc);
        }
        atomicAdd(&yout[(size_t)b * ostr + o], acc * ls);
    }
}

extern "C" void kernel_launch(void* const* d_in, const int* in_sizes, int n_in,
                              void* d_out, int out_size, void* d_ws, size_t ws_size,
                              hipStream_t stream)
{
    const float* inp = (const float*)d_in[0];
    const int2*  ind = (const int2*)d_in[1];
    const float* w1  = (const float*)d_in[2];
    const float* lam = (const float*)d_in[3];
    float* out = (float*)d_out;

    size_t cbytes = ((((size_t)K_ * CPQV) * 4) + 255) & ~(size_t)255;
    size_t tbytes = ((((size_t)K_ * TPQ) * 4) + 255) & ~(size_t)255;
    size_t YB = (size_t)(2 * YSTR) * sizeof(float);   // one 2-batch y buffer
    bool use_packed = ws_size >= cbytes + tbytes + 5 * YB;

    uint8_t* ws = (uint8_t*)d_ws;
    if (use_packed) {
        uint32_t* cornerS = (uint32_t*)ws;
        uint32_t* tailS   = (uint32_t*)(ws + cbytes);
        float* ybase = (float*)(ws + cbytes + tbytes);
        float* y[5];
        for (int i = 0; i < 5; ++i) y[i] = ybase + (size_t)i * (2 * YSTR);

        hipMemsetAsync(y[1], 0, 4 * YB, stream);                       // y1..y4
        hipMemsetAsync(out, 0, (size_t)PQ_ * 2 * sizeof(float), stream);

        long long nwork = TOT + CPQ + NPAD;
        unsigned nb = (unsigned)((nwork + 255) / 256);
        pack_all<<<dim3(nb), 256, 0, stream>>>(ind, w1, inp, cornerS, tailS, y[0]);

        const int KS_C = 10, KS_F = 6;
        dim3 gC(120, 1, 2), gF(117, 1, 2);
        for (int it = 0; it < 4; ++it)
            iter_corner<<<gC, 1024, 0, stream>>>(cornerS, y[it], y[it + 1], lam, KS_C);
        iter_final<<<gF, 1024, 0, stream>>>(cornerS, tailS, y[4], out, lam, KS_F);
    } else {
        float* y0 = (float*)ws;
        float* y1 = (float*)(ws + YB);
        copy_kernel_fb<<<(CPQ + 255) / 256, 256, 0, stream>>>(inp, y0);
        const int KS_C = 12, KS_F = 4;
        dim3 g(128, 1, 2);
        float* yin = y0; float* yout = y1;
        for (int it = 0; it < 4; ++it) {
            hipMemsetAsync(yout, 0, YB, stream);
            iter_direct<false><<<g, 1024, 0, stream>>>(ind, w1, yin, yout, lam, KS_C);
            float* t = yin; yin = yout; yout = t;
        }
        hipMemsetAsync(out, 0, (size_t)PQ_ * 2 * sizeof(float), stream);
        iter_direct<true><<<g, 1024, 0, stream>>>(ind, w1, yin, out, lam, KS_F);
    }
}